// Round 1
// baseline (2892.415 us; speedup 1.0000x reference)
//
#include <hip/hip_runtime.h>
#include <math.h>

#define N_NODES 50000
#define N_EDGES 800000
#define NFEAT 512
#define NHID 64
#define NHEAD 8
#define NCLASS 40
#define NEG_SLOPE 0.2f

// ---------------- helpers ----------------

__device__ __forceinline__ float atomicMaxF(float* addr, float value) {
    // works for any float given init = -inf
    if (value >= 0.f)
        return __int_as_float(atomicMax((int*)addr, __float_as_int(value)));
    else
        return __uint_as_float(atomicMin((unsigned int*)addr, __float_as_uint(value)));
}

__global__ void fill_f32(float* __restrict__ p, float v, int n) {
    int i = blockIdx.x * blockDim.x + threadIdx.x;
    if (i < n) p[i] = v;
}

// ---------------- layer 1 GEMM: h1[n, h*64+f] = sum_k x[n,k] * W1[h,k,f] ----------------
// block: 64 rows x 64 cols (one head per col-block). threads (16,16), 4x4 per thread.
__global__ __launch_bounds__(256) void gemm1(const float* __restrict__ x,
                                             const float* __restrict__ W1,
                                             float* __restrict__ h1) {
    __shared__ float As[64][17];
    __shared__ float Bs[16][65];
    const int h = blockIdx.x;            // 0..7 head == col block
    const int row0 = blockIdx.y * 64;
    const int tx = threadIdx.x, ty = threadIdx.y;
    const int tid = ty * 16 + tx;
    const float* Wh = W1 + h * NFEAT * NHID;
    float c[4][4] = {};
    for (int k0 = 0; k0 < NFEAT; k0 += 16) {
        int idx = tid * 4;
#pragma unroll
        for (int u = 0; u < 4; ++u) {
            int r = (idx + u) >> 4, kk = (idx + u) & 15;
            int gr = row0 + r;
            As[r][kk] = (gr < N_NODES) ? x[(size_t)gr * NFEAT + k0 + kk] : 0.f;
        }
#pragma unroll
        for (int u = 0; u < 4; ++u) {
            int q = tid + u * 256;       // 0..1023
            int kk = q >> 6, f = q & 63;
            Bs[kk][f] = Wh[(k0 + kk) * NHID + f];
        }
        __syncthreads();
#pragma unroll
        for (int kk = 0; kk < 16; ++kk) {
            float a[4], b[4];
#pragma unroll
            for (int i = 0; i < 4; ++i) a[i] = As[ty * 4 + i][kk];
#pragma unroll
            for (int j = 0; j < 4; ++j) b[j] = Bs[kk][tx * 4 + j];
#pragma unroll
            for (int i = 0; i < 4; ++i)
#pragma unroll
                for (int j = 0; j < 4; ++j) c[i][j] += a[i] * b[j];
        }
        __syncthreads();
    }
#pragma unroll
    for (int i = 0; i < 4; ++i) {
        int gr = row0 + ty * 4 + i;
        if (gr < N_NODES) {
#pragma unroll
            for (int j = 0; j < 4; ++j)
                h1[(size_t)gr * 512 + h * 64 + tx * 4 + j] = c[i][j];
        }
    }
}

// ---------------- per-node scores s1_src/s1_dst: wave per (n,h) ----------------
__global__ __launch_bounds__(256) void s1_kernel(const float* __restrict__ h1,
                                                 const float* __restrict__ a1,
                                                 float* __restrict__ s1s,
                                                 float* __restrict__ s1d) {
    int wv = blockIdx.x * 4 + (threadIdx.x >> 6);
    int lane = threadIdx.x & 63;
    if (wv >= N_NODES * NHEAD) return;
    int n = wv >> 3, h = wv & 7;
    float v = h1[(size_t)n * 512 + h * 64 + lane];
    float ps = v * a1[h * 128 + lane];
    float pd = v * a1[h * 128 + 64 + lane];
#pragma unroll
    for (int o = 32; o; o >>= 1) { ps += __shfl_down(ps, o); pd += __shfl_down(pd, o); }
    if (lane == 0) { s1s[wv] = ps; s1d[wv] = pd; }
}

// ---------------- edge passes, layer 1 (thread per (edge, head)) ----------------
__global__ void e1_max(const int* __restrict__ el,
                       const float* __restrict__ s1s, const float* __restrict__ s1d,
                       float* __restrict__ m1) {
    int g = blockIdx.x * blockDim.x + threadIdx.x;
    if (g >= N_EDGES * NHEAD) return;
    int e = g >> 3, h = g & 7;
    int src = el[e], dst = el[N_EDGES + e];
    float sc = s1s[src * 8 + h] + s1d[dst * 8 + h];
    sc = sc > 0.f ? sc : NEG_SLOPE * sc;
    atomicMaxF(&m1[dst * 8 + h], sc);
}

__global__ void e1_sum(const int* __restrict__ el,
                       const float* __restrict__ s1s, const float* __restrict__ s1d,
                       const float* __restrict__ m1, float* __restrict__ d1) {
    int g = blockIdx.x * blockDim.x + threadIdx.x;
    if (g >= N_EDGES * NHEAD) return;
    int e = g >> 3, h = g & 7;
    int src = el[e], dst = el[N_EDGES + e];
    float sc = s1s[src * 8 + h] + s1d[dst * 8 + h];
    sc = sc > 0.f ? sc : NEG_SLOPE * sc;
    float w = expf(sc - m1[dst * 8 + h]);
    atomicAdd(&d1[dst * 8 + h], w);
}

// wave per (edge, head); lane = feature
__global__ __launch_bounds__(256) void e1_agg(const int* __restrict__ el,
                                              const float* __restrict__ s1s,
                                              const float* __restrict__ s1d,
                                              const float* __restrict__ m1,
                                              const float* __restrict__ d1,
                                              const float* __restrict__ h1,
                                              float* __restrict__ agg1) {
    int wv = blockIdx.x * 4 + (threadIdx.x >> 6);
    int lane = threadIdx.x & 63;
    if (wv >= N_EDGES * NHEAD) return;
    int e = wv >> 3, h = wv & 7;
    int src = el[e], dst = el[N_EDGES + e];
    float sc = s1s[src * 8 + h] + s1d[dst * 8 + h];
    sc = sc > 0.f ? sc : NEG_SLOPE * sc;
    float w = expf(sc - m1[dst * 8 + h]);
    float alpha = w / fmaxf(d1[dst * 8 + h], 1e-16f);
    float v = alpha * h1[(size_t)src * 512 + h * 64 + lane];
    atomicAdd(&agg1[(size_t)dst * 512 + h * 64 + lane], v);
}

// ---------------- bias + ELU (in place on agg1 -> hcat) ----------------
__global__ void bias_elu(float* __restrict__ hcat, const float* __restrict__ b1) {
    int i = blockIdx.x * blockDim.x + threadIdx.x;
    if (i >= N_NODES * 512) return;
    int j = i & 511;                       // h*64+f ; b1 flat [8][64]
    float v = hcat[i] + b1[j];
    hcat[i] = v > 0.f ? v : (expf(v) - 1.f);
}

// ---------------- layer 2 GEMM + fused s2 scores: wave per row ----------------
__global__ __launch_bounds__(256) void gemm2(const float* __restrict__ hcat,
                                             const float* __restrict__ W2,
                                             const float* __restrict__ a2,
                                             float* __restrict__ h2,
                                             float* __restrict__ s2s,
                                             float* __restrict__ s2d) {
    int n = blockIdx.x * 4 + (threadIdx.x >> 6);
    int lane = threadIdx.x & 63;
    if (n >= N_NODES) return;
    float acc = 0.f;
    if (lane < NCLASS) {
        const float* row = hcat + (size_t)n * NFEAT;
#pragma unroll 8
        for (int k = 0; k < NFEAT; ++k)
            acc += row[k] * W2[k * NCLASS + lane];
    }
    float ps = (lane < NCLASS) ? acc * a2[lane] : 0.f;
    float pd = (lane < NCLASS) ? acc * a2[NCLASS + lane] : 0.f;
#pragma unroll
    for (int o = 32; o; o >>= 1) { ps += __shfl_down(ps, o); pd += __shfl_down(pd, o); }
    if (lane == 0) { s2s[n] = ps; s2d[n] = pd; }
    if (lane < NCLASS) h2[(size_t)n * NCLASS + lane] = acc;
}

// ---------------- edge passes, layer 2 ----------------
__global__ void e2_max(const int* __restrict__ el,
                       const float* __restrict__ s2s, const float* __restrict__ s2d,
                       float* __restrict__ m2) {
    int e = blockIdx.x * blockDim.x + threadIdx.x;
    if (e >= N_EDGES) return;
    int src = el[e], dst = el[N_EDGES + e];
    float sc = s2s[src] + s2d[dst];
    sc = sc > 0.f ? sc : NEG_SLOPE * sc;
    atomicMaxF(&m2[dst], sc);
}

__global__ void e2_sum(const int* __restrict__ el,
                       const float* __restrict__ s2s, const float* __restrict__ s2d,
                       const float* __restrict__ m2, float* __restrict__ d2) {
    int e = blockIdx.x * blockDim.x + threadIdx.x;
    if (e >= N_EDGES) return;
    int src = el[e], dst = el[N_EDGES + e];
    float sc = s2s[src] + s2d[dst];
    sc = sc > 0.f ? sc : NEG_SLOPE * sc;
    float w = expf(sc - m2[dst]);
    atomicAdd(&d2[dst], w);
}

__global__ __launch_bounds__(256) void e2_agg(const int* __restrict__ el,
                                              const float* __restrict__ s2s,
                                              const float* __restrict__ s2d,
                                              const float* __restrict__ m2,
                                              const float* __restrict__ d2,
                                              const float* __restrict__ h2,
                                              float* __restrict__ agg2) {
    int e = blockIdx.x * 4 + (threadIdx.x >> 6);
    int lane = threadIdx.x & 63;
    if (e >= N_EDGES) return;
    int src = el[e], dst = el[N_EDGES + e];
    float sc = s2s[src] + s2d[dst];
    sc = sc > 0.f ? sc : NEG_SLOPE * sc;
    float w = expf(sc - m2[dst]);
    float alpha = w / fmaxf(d2[dst], 1e-16f);
    if (lane < NCLASS) {
        float v = alpha * h2[(size_t)src * NCLASS + lane];
        atomicAdd(&agg2[(size_t)dst * NCLASS + lane], v);
    }
}

// ---------------- bias + log_softmax: wave per node ----------------
__global__ __launch_bounds__(256) void final_k(const float* __restrict__ agg2,
                                               const float* __restrict__ b2,
                                               float* __restrict__ out) {
    int n = blockIdx.x * 4 + (threadIdx.x >> 6);
    int lane = threadIdx.x & 63;
    if (n >= N_NODES) return;
    float v = (lane < NCLASS) ? agg2[(size_t)n * NCLASS + lane] + b2[lane] : -INFINITY;
    float m = v;
#pragma unroll
    for (int o = 32; o; o >>= 1) m = fmaxf(m, __shfl_down(m, o));
    m = __shfl(m, 0);
    float ex = (lane < NCLASS) ? expf(v - m) : 0.f;
    float s = ex;
#pragma unroll
    for (int o = 32; o; o >>= 1) s += __shfl_down(s, o);
    s = __shfl(s, 0);
    float ls = logf(s);
    if (lane < NCLASS) out[(size_t)n * NCLASS + lane] = v - m - ls;
}

// ---------------- launch ----------------

extern "C" void kernel_launch(void* const* d_in, const int* in_sizes, int n_in,
                              void* d_out, int out_size, void* d_ws, size_t ws_size,
                              hipStream_t stream) {
    const float* x  = (const float*)d_in[0];
    const int*   el = (const int*)d_in[1];
    const float* W1 = (const float*)d_in[2];
    const float* a1 = (const float*)d_in[3];
    const float* b1 = (const float*)d_in[4];
    const float* W2 = (const float*)d_in[5];
    const float* a2 = (const float*)d_in[6];
    const float* b2 = (const float*)d_in[7];
    float* out = (float*)d_out;
    float* ws  = (float*)d_ws;

    // workspace layout (floats)
    float* h1   = ws;                       // 25,600,000
    float* hcat = ws + 25600000;            // 25,600,000 (agg1, then ELU in place)
    float* h2   = ws + 51200000;            //  2,000,000
    float* agg2 = ws + 53200000;            //  2,000,000
    float* s1s  = ws + 55200000;            //    400,000
    float* s1d  = ws + 55600000;            //    400,000
    float* s2s  = ws + 56000000;            //     50,000
    float* s2d  = ws + 56050000;            //     50,000
    float* m1   = ws + 56100000;            //    400,000
    float* m2   = ws + 56500000;            //     50,000  (m1+m2 contiguous)
    float* d1   = ws + 56550000;            //    400,000
    float* d2   = ws + 56950000;            //     50,000  (d1+d2 contiguous)
    // total 57,000,000 floats = 228 MB

    // init: zeros for hcat(+h2+agg2 contiguous) and d1+d2; -inf for m1+m2
    hipMemsetAsync(hcat, 0, (size_t)(25600000 + 2000000 + 2000000) * 4, stream);
    hipMemsetAsync(d1, 0, (size_t)450000 * 4, stream);
    fill_f32<<<(450000 + 255) / 256, 256, 0, stream>>>(m1, -INFINITY, 450000);

    // layer 1
    dim3 g1(8, (N_NODES + 63) / 64);
    gemm1<<<g1, dim3(16, 16), 0, stream>>>(x, W1, h1);
    s1_kernel<<<(N_NODES * NHEAD + 3) / 4, 256, 0, stream>>>(h1, a1, s1s, s1d);
    e1_max<<<(N_EDGES * NHEAD + 255) / 256, 256, 0, stream>>>(el, s1s, s1d, m1);
    e1_sum<<<(N_EDGES * NHEAD + 255) / 256, 256, 0, stream>>>(el, s1s, s1d, m1, d1);
    e1_agg<<<(N_EDGES * NHEAD + 3) / 4, 256, 0, stream>>>(el, s1s, s1d, m1, d1, h1, hcat);
    bias_elu<<<(N_NODES * 512 + 255) / 256, 256, 0, stream>>>(hcat, b1);

    // layer 2
    gemm2<<<(N_NODES + 3) / 4, 256, 0, stream>>>(hcat, W2, a2, h2, s2s, s2d);
    e2_max<<<(N_EDGES + 255) / 256, 256, 0, stream>>>(el, s2s, s2d, m2);
    e2_sum<<<(N_EDGES + 255) / 256, 256, 0, stream>>>(el, s2s, s2d, m2, d2);
    e2_agg<<<(N_EDGES + 3) / 4, 256, 0, stream>>>(el, s2s, s2d, m2, d2, h2, agg2);
    final_k<<<(N_NODES + 3) / 4, 256, 0, stream>>>(agg2, b2, out);
}

// Round 2
// 1992.910 us; speedup vs baseline: 1.4514x; 1.4514x over previous
//
#include <hip/hip_runtime.h>
#include <math.h>

#define N_NODES 50000
#define N_EDGES 800000
#define NFEAT 512
#define NHID 64
#define NHEAD 8
#define NCLASS 40
#define NEG_SLOPE 0.2f

// ---------------- CSR build ----------------

__global__ void count_deg(const int* __restrict__ el, int* __restrict__ deg) {
    int e = blockIdx.x * blockDim.x + threadIdx.x;
    if (e < N_EDGES) atomicAdd(&deg[el[N_EDGES + e]], 1);
}

// single-block scan over 50k degrees -> ptr (exclusive, +1 shifted) and cursor (exclusive)
__global__ __launch_bounds__(256) void scan_k(const int* __restrict__ deg,
                                              int* __restrict__ ptr,
                                              int* __restrict__ cursor) {
    __shared__ int sm[256];
    int run = 0;
    if (threadIdx.x == 0) ptr[0] = 0;
    for (int base = 0; base < N_NODES; base += 256) {
        int i = base + threadIdx.x;
        int v = (i < N_NODES) ? deg[i] : 0;
        sm[threadIdx.x] = v;
        __syncthreads();
        int val = v;
#pragma unroll
        for (int off = 1; off < 256; off <<= 1) {
            int t = (threadIdx.x >= off) ? sm[threadIdx.x - off] : 0;
            __syncthreads();
            val += t;
            sm[threadIdx.x] = val;
            __syncthreads();
        }
        if (i < N_NODES) { ptr[i + 1] = run + val; cursor[i] = run + val - v; }
        int tot = sm[255];
        __syncthreads();
        run += tot;
    }
}

__global__ void scatter_k(const int* __restrict__ el, int* __restrict__ cursor,
                          int* __restrict__ esrc) {
    int e = blockIdx.x * blockDim.x + threadIdx.x;
    if (e >= N_EDGES) return;
    int dst = el[N_EDGES + e];
    int p = atomicAdd(&cursor[dst], 1);
    esrc[p] = el[e];
}

// ---------------- layer 1 GEMM: h1[n, h*64+f] = sum_k x[n,k] * W1[h,k,f] ----------------
__global__ __launch_bounds__(256) void gemm1(const float* __restrict__ x,
                                             const float* __restrict__ W1,
                                             float* __restrict__ h1) {
    __shared__ float As[64][17];
    __shared__ float Bs[16][65];
    const int h = blockIdx.x;            // 0..7 head == col block
    const int row0 = blockIdx.y * 64;
    const int tx = threadIdx.x, ty = threadIdx.y;
    const int tid = ty * 16 + tx;
    const float* Wh = W1 + h * NFEAT * NHID;
    float c[4][4] = {};
    for (int k0 = 0; k0 < NFEAT; k0 += 16) {
        int idx = tid * 4;
#pragma unroll
        for (int u = 0; u < 4; ++u) {
            int r = (idx + u) >> 4, kk = (idx + u) & 15;
            int gr = row0 + r;
            As[r][kk] = (gr < N_NODES) ? x[(size_t)gr * NFEAT + k0 + kk] : 0.f;
        }
#pragma unroll
        for (int u = 0; u < 4; ++u) {
            int q = tid + u * 256;       // 0..1023
            int kk = q >> 6, f = q & 63;
            Bs[kk][f] = Wh[(k0 + kk) * NHID + f];
        }
        __syncthreads();
#pragma unroll
        for (int kk = 0; kk < 16; ++kk) {
            float a[4], b[4];
#pragma unroll
            for (int i = 0; i < 4; ++i) a[i] = As[ty * 4 + i][kk];
#pragma unroll
            for (int j = 0; j < 4; ++j) b[j] = Bs[kk][tx * 4 + j];
#pragma unroll
            for (int i = 0; i < 4; ++i)
#pragma unroll
                for (int j = 0; j < 4; ++j) c[i][j] += a[i] * b[j];
        }
        __syncthreads();
    }
#pragma unroll
    for (int i = 0; i < 4; ++i) {
        int gr = row0 + ty * 4 + i;
        if (gr < N_NODES) {
#pragma unroll
            for (int j = 0; j < 4; ++j)
                h1[(size_t)gr * 512 + h * 64 + tx * 4 + j] = c[i][j];
        }
    }
}

// ---------------- per-node scores s1_src/s1_dst: wave per (n,h) ----------------
__global__ __launch_bounds__(256) void s1_kernel(const float* __restrict__ h1,
                                                 const float* __restrict__ a1,
                                                 float* __restrict__ s1s,
                                                 float* __restrict__ s1d) {
    int wv = blockIdx.x * 4 + (threadIdx.x >> 6);
    int lane = threadIdx.x & 63;
    if (wv >= N_NODES * NHEAD) return;
    int n = wv >> 3, h = wv & 7;
    float v = h1[(size_t)n * 512 + h * 64 + lane];
    float ps = v * a1[h * 128 + lane];
    float pd = v * a1[h * 128 + 64 + lane];
#pragma unroll
    for (int o = 32; o; o >>= 1) { ps += __shfl_down(ps, o); pd += __shfl_down(pd, o); }
    if (lane == 0) { s1s[wv] = ps; s1d[wv] = pd; }
}

// ---------------- fused layer-1 attention: wave per (dst, head), online softmax ----------------
// fuses e1_max + e1_sum + e1_agg + bias + ELU. no atomics.
__global__ __launch_bounds__(256) void att1(const int* __restrict__ ptr,
                                            const int* __restrict__ esrc,
                                            const float* __restrict__ s1s,
                                            const float* __restrict__ s1d,
                                            const float* __restrict__ h1,
                                            const float* __restrict__ b1,
                                            float* __restrict__ hcat) {
    int wv = blockIdx.x * 4 + (threadIdx.x >> 6);
    int lane = threadIdx.x & 63;
    if (wv >= N_NODES * NHEAD) return;
    int n = wv >> 3, h = wv & 7;
    int beg = ptr[n], end = ptr[n + 1];
    float sd = s1d[n * 8 + h];
    float m = -INFINITY, den = 0.f, acc = 0.f;
    for (int i = beg; i < end; ++i) {
        int src = esrc[i];
        float sc = s1s[src * 8 + h] + sd;
        sc = sc > 0.f ? sc : NEG_SLOPE * sc;
        float nm = fmaxf(m, sc);
        float scale = __expf(m - nm);    // m=-inf first iter -> 0
        float w = __expf(sc - nm);
        float hv = h1[(size_t)src * 512 + h * 64 + lane];
        den = den * scale + w;
        acc = acc * scale + w * hv;
        m = nm;
    }
    float outv = acc / fmaxf(den, 1e-16f) + b1[h * 64 + lane];
    outv = outv > 0.f ? outv : (__expf(outv) - 1.f);   // ELU
    hcat[(size_t)n * 512 + h * 64 + lane] = outv;
}

// ---------------- layer 2 GEMM + fused s2 scores: wave per row ----------------
__global__ __launch_bounds__(256) void gemm2(const float* __restrict__ hcat,
                                             const float* __restrict__ W2,
                                             const float* __restrict__ a2,
                                             float* __restrict__ h2,
                                             float* __restrict__ s2s,
                                             float* __restrict__ s2d) {
    int n = blockIdx.x * 4 + (threadIdx.x >> 6);
    int lane = threadIdx.x & 63;
    if (n >= N_NODES) return;
    float acc = 0.f;
    if (lane < NCLASS) {
        const float* row = hcat + (size_t)n * NFEAT;
#pragma unroll 8
        for (int k = 0; k < NFEAT; ++k)
            acc += row[k] * W2[k * NCLASS + lane];
    }
    float ps = (lane < NCLASS) ? acc * a2[lane] : 0.f;
    float pd = (lane < NCLASS) ? acc * a2[NCLASS + lane] : 0.f;
#pragma unroll
    for (int o = 32; o; o >>= 1) { ps += __shfl_down(ps, o); pd += __shfl_down(pd, o); }
    if (lane == 0) { s2s[n] = ps; s2d[n] = pd; }
    if (lane < NCLASS) h2[(size_t)n * NCLASS + lane] = acc;
}

// ---------------- fused layer-2 attention + log_softmax: wave per dst ----------------
__global__ __launch_bounds__(256) void att2(const int* __restrict__ ptr,
                                            const int* __restrict__ esrc,
                                            const float* __restrict__ s2s,
                                            const float* __restrict__ s2d,
                                            const float* __restrict__ h2,
                                            const float* __restrict__ b2,
                                            float* __restrict__ out) {
    int n = blockIdx.x * 4 + (threadIdx.x >> 6);
    int lane = threadIdx.x & 63;
    if (n >= N_NODES) return;
    int beg = ptr[n], end = ptr[n + 1];
    float sd = s2d[n];
    float m = -INFINITY, den = 0.f, acc = 0.f;
    for (int i = beg; i < end; ++i) {
        int src = esrc[i];
        float sc = s2s[src] + sd;
        sc = sc > 0.f ? sc : NEG_SLOPE * sc;
        float nm = fmaxf(m, sc);
        float scale = __expf(m - nm);
        float w = __expf(sc - nm);
        float hv = (lane < NCLASS) ? h2[(size_t)src * NCLASS + lane] : 0.f;
        den = den * scale + w;
        acc = acc * scale + w * hv;
        m = nm;
    }
    float v = (lane < NCLASS) ? acc / fmaxf(den, 1e-16f) + b2[lane] : -INFINITY;
    // fused log_softmax over 40 classes
    float mx = v;
#pragma unroll
    for (int o = 32; o; o >>= 1) mx = fmaxf(mx, __shfl_down(mx, o));
    mx = __shfl(mx, 0);
    float ex = (lane < NCLASS) ? __expf(v - mx) : 0.f;
    float s = ex;
#pragma unroll
    for (int o = 32; o; o >>= 1) s += __shfl_down(s, o);
    s = __shfl(s, 0);
    float ls = __logf(s);
    if (lane < NCLASS) out[(size_t)n * NCLASS + lane] = v - mx - ls;
}

// ---------------- launch ----------------

extern "C" void kernel_launch(void* const* d_in, const int* in_sizes, int n_in,
                              void* d_out, int out_size, void* d_ws, size_t ws_size,
                              hipStream_t stream) {
    const float* x  = (const float*)d_in[0];
    const int*   el = (const int*)d_in[1];
    const float* W1 = (const float*)d_in[2];
    const float* a1 = (const float*)d_in[3];
    const float* b1 = (const float*)d_in[4];
    const float* W2 = (const float*)d_in[5];
    const float* a2 = (const float*)d_in[6];
    const float* b2 = (const float*)d_in[7];
    float* out = (float*)d_out;
    float* ws  = (float*)d_ws;

    // workspace layout (floats / ints)
    float* h1   = ws;                       // 25,600,000
    float* hcat = ws + 25600000;            // 25,600,000
    float* h2   = ws + 51200000;            //  2,000,000
    float* s1s  = ws + 53200000;            //    400,000
    float* s1d  = ws + 53600000;            //    400,000
    float* s2s  = ws + 54000000;            //     50,000
    float* s2d  = ws + 54050000;            //     50,000
    int*   deg    = (int*)(ws + 54100000);  //     50,000
    int*   ptr    = (int*)(ws + 54150000);  //     50,001
    int*   cursor = (int*)(ws + 54200001);  //     50,000
    int*   esrc   = (int*)(ws + 54250001);  //    800,000
    // total ~55.05M elems = 220 MB

    // ---- CSR build (per launch; edge_list is re-poisoned input) ----
    hipMemsetAsync(deg, 0, (size_t)N_NODES * 4, stream);
    count_deg<<<(N_EDGES + 255) / 256, 256, 0, stream>>>(el, deg);
    scan_k<<<1, 256, 0, stream>>>(deg, ptr, cursor);
    scatter_k<<<(N_EDGES + 255) / 256, 256, 0, stream>>>(el, cursor, esrc);

    // ---- layer 1 ----
    dim3 g1(8, (N_NODES + 63) / 64);
    gemm1<<<g1, dim3(16, 16), 0, stream>>>(x, W1, h1);
    s1_kernel<<<(N_NODES * NHEAD + 3) / 4, 256, 0, stream>>>(h1, a1, s1s, s1d);
    att1<<<(N_NODES * NHEAD + 3) / 4, 256, 0, stream>>>(ptr, esrc, s1s, s1d, h1, b1, hcat);

    // ---- layer 2 ----
    gemm2<<<(N_NODES + 3) / 4, 256, 0, stream>>>(hcat, W2, a2, h2, s2s, s2d);
    att2<<<(N_NODES + 3) / 4, 256, 0, stream>>>(ptr, esrc, s2s, s2d, h2, b2, out);
}

// Round 3
// 784.407 us; speedup vs baseline: 3.6874x; 2.5407x over previous
//
#include <hip/hip_runtime.h>
#include <math.h>

#define N_NODES 50000
#define N_EDGES 800000
#define NFEAT 512
#define NHID 64
#define NHEAD 8
#define NCLASS 40
#define NEG_SLOPE 0.2f

#define N_RT 3125           // 50000/16 row tiles
#define N_RT_PAD 3128       // padded to multiple of 8 (gemm1 block = 8 rowtiles)

typedef __attribute__((ext_vector_type(8))) short short8;
typedef __attribute__((ext_vector_type(4))) float f32x4;

__device__ __forceinline__ float bf2f(short s) {
    return __uint_as_float(((unsigned)(unsigned short)s) << 16);
}
__device__ __forceinline__ short f2bf(float f) {
    unsigned u = __float_as_uint(f);
    unsigned r = (u + 0x7FFFu + ((u >> 16) & 1u)) >> 16;
    return (short)(unsigned short)r;
}

// ---------------- CSR build ----------------

__global__ void count_deg(const int* __restrict__ el, int* __restrict__ deg) {
    int e = blockIdx.x * blockDim.x + threadIdx.x;
    if (e < N_EDGES) atomicAdd(&deg[el[N_EDGES + e]], 1);
}

__global__ __launch_bounds__(256) void scan_k(const int* __restrict__ deg,
                                              int* __restrict__ ptr,
                                              int* __restrict__ cursor) {
    __shared__ int sm[256];
    int run = 0;
    if (threadIdx.x == 0) ptr[0] = 0;
    for (int base = 0; base < N_NODES; base += 256) {
        int i = base + threadIdx.x;
        int v = (i < N_NODES) ? deg[i] : 0;
        sm[threadIdx.x] = v;
        __syncthreads();
        int val = v;
#pragma unroll
        for (int off = 1; off < 256; off <<= 1) {
            int t = (threadIdx.x >= off) ? sm[threadIdx.x - off] : 0;
            __syncthreads();
            val += t;
            sm[threadIdx.x] = val;
            __syncthreads();
        }
        if (i < N_NODES) { ptr[i + 1] = run + val; cursor[i] = run + val - v; }
        int tot = sm[255];
        __syncthreads();
        run += tot;
    }
}

__global__ void scatter_k(const int* __restrict__ el, int* __restrict__ cursor,
                          int* __restrict__ esrc) {
    int e = blockIdx.x * blockDim.x + threadIdx.x;
    if (e >= N_EDGES) return;
    int dst = el[N_EDGES + e];
    int p = atomicAdd(&cursor[dst], 1);
    esrc[p] = el[e];
}

// ---------------- cast x fp32 -> bf16 in MFMA A-fragment layout ----------------
// xp[((rt*16 + ks)*64 + l)*8 + j] = x[rt*16 + (l&15)][ks*32 + (l>>4)*8 + j]
__global__ __launch_bounds__(256) void cast_x(const float* __restrict__ x,
                                              short* __restrict__ xp) {
    int t = blockIdx.x * 256 + threadIdx.x;       // < N_RT_PAD*16*64
    int l = t & 63, ks = (t >> 6) & 15, rt = t >> 10;
    short8 o;
    if (rt >= N_RT) {
#pragma unroll
        for (int j = 0; j < 8; ++j) o[j] = 0;
    } else {
        int row = rt * 16 + (l & 15);
        int col = ks * 32 + (l >> 4) * 8;
        const float* p = x + (size_t)row * NFEAT + col;
        float4 v0 = *(const float4*)p;
        float4 v1 = *(const float4*)(p + 4);
        o[0] = f2bf(v0.x); o[1] = f2bf(v0.y); o[2] = f2bf(v0.z); o[3] = f2bf(v0.w);
        o[4] = f2bf(v1.x); o[5] = f2bf(v1.y); o[6] = f2bf(v1.z); o[7] = f2bf(v1.w);
    }
    *(short8*)(xp + (size_t)t * 8) = o;
}

// ---------------- repack W1, W2 into MFMA B-fragment layout (bf16) ----------------
// Wp1[(((g*16+ks)*8+ct)*64+l)*8+j] = W1[head][ks*32+(l>>4)*8+j][f], c=g*128+ct*16+(l&15)
// Wp2[((ks*3+ct)*64+l)*8+j]        = W2[ks*32+(l>>4)*8+j][ct*16+(l&15)] (pad col>=40 -> 0)
__global__ __launch_bounds__(256) void repack_w(const float* __restrict__ W1,
                                                const float* __restrict__ W2,
                                                short* __restrict__ Wp1,
                                                short* __restrict__ Wp2) {
    int t = blockIdx.x * 256 + threadIdx.x;
    if (t < 32768) {
        int l = t & 63, ct = (t >> 6) & 7, ks = (t >> 9) & 15, g = t >> 13;
        int c = g * 128 + ct * 16 + (l & 15);
        int head = c >> 6, f = c & 63;
        int k0 = ks * 32 + (l >> 4) * 8;
        short8 o;
#pragma unroll
        for (int j = 0; j < 8; ++j)
            o[j] = f2bf(W1[(size_t)head * NFEAT * NHID + (k0 + j) * NHID + f]);
        *(short8*)(Wp1 + (size_t)t * 8) = o;
    } else if (t < 32768 + 3072) {
        int u = t - 32768;
        int l = u & 63;
        int kc = u >> 6;                 // ks*3+ct
        int ct = kc % 3, ks = kc / 3;
        int col = ct * 16 + (l & 15);
        int k0 = ks * 32 + (l >> 4) * 8;
        short8 o;
#pragma unroll
        for (int j = 0; j < 8; ++j)
            o[j] = (col < NCLASS) ? f2bf(W2[(size_t)(k0 + j) * NCLASS + col]) : (short)0;
        *(short8*)(Wp2 + (size_t)u * 8) = o;
    }
}

// ---------------- gemm1: MFMA, no LDS. h1[n][512] bf16 row-major ----------------
// grid (4 colgroups, 391 rowblocks), 256 thr = 4 waves; wave: 2 rowtiles x 8 coltiles
__global__ __launch_bounds__(256) void gemm1(const short* __restrict__ xp,
                                             const short* __restrict__ Wp1,
                                             short* __restrict__ h1) {
    int w = threadIdx.x >> 6, l = threadIdx.x & 63;
    int g = blockIdx.x;
    int rt0 = blockIdx.y * 8 + w * 2;
    f32x4 acc[2][8];
#pragma unroll
    for (int i = 0; i < 2; ++i)
#pragma unroll
        for (int ct = 0; ct < 8; ++ct) acc[i][ct] = (f32x4){0.f, 0.f, 0.f, 0.f};

#pragma unroll 2
    for (int ks = 0; ks < 16; ++ks) {
        short8 a0 = *(const short8*)(xp + ((size_t)(rt0 * 16 + ks) * 64 + l) * 8);
        short8 a1v = *(const short8*)(xp + ((size_t)((rt0 + 1) * 16 + ks) * 64 + l) * 8);
        const short* bp = Wp1 + (size_t)(g * 16 + ks) * 4096 + l * 8;
#pragma unroll
        for (int ct = 0; ct < 8; ++ct) {
            short8 b = *(const short8*)(bp + ct * 512);
            acc[0][ct] = __builtin_amdgcn_mfma_f32_16x16x32_bf16(a0, b, acc[0][ct], 0, 0, 0);
            acc[1][ct] = __builtin_amdgcn_mfma_f32_16x16x32_bf16(a1v, b, acc[1][ct], 0, 0, 0);
        }
    }
    int colbase = g * 128 + (l & 15);
    int rbase = (l >> 4) * 4;
#pragma unroll
    for (int i = 0; i < 2; ++i)
#pragma unroll
        for (int r = 0; r < 4; ++r) {
            int row = (rt0 + i) * 16 + rbase + r;
            if (row < N_NODES) {
#pragma unroll
                for (int ct = 0; ct < 8; ++ct)
                    h1[(size_t)row * 512 + colbase + ct * 16] = f2bf(acc[i][ct][r]);
            }
        }
}

// ---------------- s1 scores: wave per node, all heads; lane = 8 contig feats ----------------
__global__ __launch_bounds__(256) void s1_kernel(const short* __restrict__ h1,
                                                 const float* __restrict__ a1,
                                                 float* __restrict__ s1s,
                                                 float* __restrict__ s1d) {
    int n = blockIdx.x * 4 + (threadIdx.x >> 6);
    int l = threadIdx.x & 63;
    if (n >= N_NODES) return;
    short8 hv = *(const short8*)(h1 + (size_t)n * 512 + l * 8);
    int h = l >> 3, fb = (l & 7) * 8;
    float ps = 0.f, pd = 0.f;
#pragma unroll
    for (int j = 0; j < 8; ++j) {
        float v = bf2f(hv[j]);
        ps += v * a1[h * 128 + fb + j];
        pd += v * a1[h * 128 + 64 + fb + j];
    }
#pragma unroll
    for (int mask = 1; mask < 8; mask <<= 1) {
        ps += __shfl_xor(ps, mask);
        pd += __shfl_xor(pd, mask);
    }
    if ((l & 7) == 0) { s1s[n * 8 + h] = ps; s1d[n * 8 + h] = pd; }
}

// ---------------- fused layer-1 attention: wave per dst, ALL heads ----------------
// lane l owns features c = l*8..l*8+7 (head = l>>3). Writes hcat in A-frag layout.
__global__ __launch_bounds__(256) void att1(const int* __restrict__ ptr,
                                            const int* __restrict__ esrc,
                                            const float* __restrict__ s1s,
                                            const float* __restrict__ s1d,
                                            const short* __restrict__ h1,
                                            const float* __restrict__ b1,
                                            short* __restrict__ hcatp) {
    int n = blockIdx.x * 4 + (threadIdx.x >> 6);
    int l = threadIdx.x & 63;
    if (n >= N_NODES) return;
    int beg = ptr[n], end = ptr[n + 1];
    int h = l >> 3;
    float sd = s1d[n * 8 + h];
    float m = -INFINITY, den = 0.f;
    float acc[8] = {0.f, 0.f, 0.f, 0.f, 0.f, 0.f, 0.f, 0.f};
    for (int i = beg; i < end; ++i) {
        int src = esrc[i];
        float sc = s1s[src * 8 + h] + sd;
        sc = sc > 0.f ? sc : NEG_SLOPE * sc;
        float nm = fmaxf(m, sc);
        float scale = __expf(m - nm);     // first iter: exp(-inf)=0
        float wgt = __expf(sc - nm);
        den = den * scale + wgt;
        short8 hv = *(const short8*)(h1 + (size_t)src * 512 + l * 8);
#pragma unroll
        for (int j = 0; j < 8; ++j) acc[j] = acc[j] * scale + wgt * bf2f(hv[j]);
        m = nm;
    }
    float rden = 1.f / fmaxf(den, 1e-16f);
    short8 o;
#pragma unroll
    for (int j = 0; j < 8; ++j) {
        float v = acc[j] * rden + b1[l * 8 + j];
        v = v > 0.f ? v : (__expf(v) - 1.f);      // ELU
        o[j] = f2bf(v);
    }
    // frag layout: rt=n>>4, ks=l>>2, lane'=(l&3)*16+(n&15), j contiguous
    size_t addr = (((size_t)(n >> 4) * 16 + (l >> 2)) * 64 + (l & 3) * 16 + (n & 15)) * 8;
    *(short8*)(hcatp + addr) = o;
}

// ---------------- gemm2: MFMA + fused s2 scores. wave per rowtile ----------------
__global__ __launch_bounds__(256) void gemm2(const short* __restrict__ hcatp,
                                             const short* __restrict__ Wp2,
                                             const float* __restrict__ a2,
                                             short* __restrict__ h2,
                                             float* __restrict__ s2s,
                                             float* __restrict__ s2d) {
    int w = threadIdx.x >> 6, l = threadIdx.x & 63;
    int rt = blockIdx.x * 4 + w;                  // < N_RT_PAD
    f32x4 acc[3];
#pragma unroll
    for (int ct = 0; ct < 3; ++ct) acc[ct] = (f32x4){0.f, 0.f, 0.f, 0.f};
#pragma unroll 2
    for (int ks = 0; ks < 16; ++ks) {
        short8 a = *(const short8*)(hcatp + ((size_t)(rt * 16 + ks) * 64 + l) * 8);
        const short* bp = Wp2 + (size_t)(ks * 3) * 512 + l * 8;
#pragma unroll
        for (int ct = 0; ct < 3; ++ct) {
            short8 b = *(const short8*)(bp + ct * 512);
            acc[ct] = __builtin_amdgcn_mfma_f32_16x16x32_bf16(a, b, acc[ct], 0, 0, 0);
        }
    }
    float ps[4] = {0.f, 0.f, 0.f, 0.f}, pd[4] = {0.f, 0.f, 0.f, 0.f};
    int cl = l & 15, rb = (l >> 4) * 4;
#pragma unroll
    for (int ct = 0; ct < 3; ++ct) {
        int col = ct * 16 + cl;
        if (col < NCLASS) {
#pragma unroll
            for (int r = 0; r < 4; ++r) {
                ps[r] += acc[ct][r] * a2[col];
                pd[r] += acc[ct][r] * a2[NCLASS + col];
                int row = rt * 16 + rb + r;
                if (row < N_NODES) h2[(size_t)row * NCLASS + col] = f2bf(acc[ct][r]);
            }
        }
    }
#pragma unroll
    for (int mask = 1; mask < 16; mask <<= 1)
#pragma unroll
        for (int r = 0; r < 4; ++r) {
            ps[r] += __shfl_xor(ps[r], mask);
            pd[r] += __shfl_xor(pd[r], mask);
        }
    if (cl == 0) {
#pragma unroll
        for (int r = 0; r < 4; ++r) {
            int row = rt * 16 + rb + r;
            if (row < N_NODES) { s2s[row] = ps[r]; s2d[row] = pd[r]; }
        }
    }
}

// ---------------- fused layer-2 attention + log_softmax: wave per dst ----------------
__global__ __launch_bounds__(256) void att2(const int* __restrict__ ptr,
                                            const int* __restrict__ esrc,
                                            const float* __restrict__ s2s,
                                            const float* __restrict__ s2d,
                                            const short* __restrict__ h2,
                                            const float* __restrict__ b2,
                                            float* __restrict__ out) {
    int n = blockIdx.x * 4 + (threadIdx.x >> 6);
    int l = threadIdx.x & 63;
    if (n >= N_NODES) return;
    int beg = ptr[n], end = ptr[n + 1];
    float sd = s2d[n];
    float m = -INFINITY, den = 0.f, acc = 0.f;
    for (int i = beg; i < end; ++i) {
        int src = esrc[i];
        float sc = s2s[src] + sd;
        sc = sc > 0.f ? sc : NEG_SLOPE * sc;
        float nm = fmaxf(m, sc);
        float scale = __expf(m - nm);
        float wgt = __expf(sc - nm);
        float hv = (l < NCLASS) ? bf2f(h2[(size_t)src * NCLASS + l]) : 0.f;
        den = den * scale + wgt;
        acc = acc * scale + wgt * hv;
        m = nm;
    }
    float v = (l < NCLASS) ? acc / fmaxf(den, 1e-16f) + b2[l] : -INFINITY;
    float mx = v;
#pragma unroll
    for (int o = 32; o; o >>= 1) mx = fmaxf(mx, __shfl_down(mx, o));
    mx = __shfl(mx, 0);
    float ex = (l < NCLASS) ? __expf(v - mx) : 0.f;
    float s = ex;
#pragma unroll
    for (int o = 32; o; o >>= 1) s += __shfl_down(s, o);
    s = __shfl(s, 0);
    float ls = __logf(s);
    if (l < NCLASS) out[(size_t)n * NCLASS + l] = v - mx - ls;
}

// ---------------- launch ----------------

extern "C" void kernel_launch(void* const* d_in, const int* in_sizes, int n_in,
                              void* d_out, int out_size, void* d_ws, size_t ws_size,
                              hipStream_t stream) {
    const float* x  = (const float*)d_in[0];
    const int*   el = (const int*)d_in[1];
    const float* W1 = (const float*)d_in[2];
    const float* a1 = (const float*)d_in[3];
    const float* b1 = (const float*)d_in[4];
    const float* W2 = (const float*)d_in[5];
    const float* a2 = (const float*)d_in[6];
    const float* b2 = (const float*)d_in[7];
    float* out = (float*)d_out;

    // workspace carve (shorts first, then floats, then ints)
    short* sbase = (short*)d_ws;
    short* xp    = sbase;                          // 25,624,576
    short* hcatp = sbase + 25624576;               // 25,624,576
    short* h1    = sbase + 51249152;               // 25,600,000
    short* Wp1   = sbase + 76849152;               //    262,144
    short* Wp2   = sbase + 77111296;               //     24,576
    short* h2    = sbase + 77135872;               //  2,000,000
    float* fbase = (float*)(sbase + 79135872);
    float* s1s   = fbase;                          //    400,000
    float* s1d   = fbase + 400000;                 //    400,000
    float* s2s   = fbase + 800000;                 //     50,000
    float* s2d   = fbase + 850000;                 //     50,000
    int*   ibase = (int*)(fbase + 900000);
    int*   deg    = ibase;                         //     50,000
    int*   ptr    = ibase + 50000;                 //     50,001
    int*   cursor = ibase + 100001;                //     50,000
    int*   esrc   = ibase + 150001;                //    800,000
    // total ~165.7 MB

    // ---- CSR build ----
    hipMemsetAsync(deg, 0, (size_t)N_NODES * 4, stream);
    count_deg<<<(N_EDGES + 255) / 256, 256, 0, stream>>>(el, deg);
    scan_k<<<1, 256, 0, stream>>>(deg, ptr, cursor);
    scatter_k<<<(N_EDGES + 255) / 256, 256, 0, stream>>>(el, cursor, esrc);

    // ---- operand packing ----
    cast_x<<<(N_RT_PAD * 1024) / 256, 256, 0, stream>>>(x, xp);
    repack_w<<<(35840 + 255) / 256, 256, 0, stream>>>(W1, W2, Wp1, Wp2);

    // ---- layer 1 ----
    gemm1<<<dim3(4, N_RT_PAD / 8), 256, 0, stream>>>(xp, Wp1, h1);
    s1_kernel<<<(N_NODES + 3) / 4, 256, 0, stream>>>(h1, a1, s1s, s1d);
    att1<<<(N_NODES + 3) / 4, 256, 0, stream>>>(ptr, esrc, s1s, s1d, h1, b1, hcatp);

    // ---- layer 2 ----
    gemm2<<<N_RT_PAD / 4, 256, 0, stream>>>(hcatp, Wp2, a2, h2, s2s, s2d);
    att2<<<(N_NODES + 3) / 4, 256, 0, stream>>>(ptr, esrc, s2s, s2d, h2, b2, out);
}

// Round 4
// 619.357 us; speedup vs baseline: 4.6700x; 1.2665x over previous
//
#include <hip/hip_runtime.h>
#include <math.h>

#define N_NODES 50000
#define N_EDGES 800000
#define NFEAT 512
#define NHID 64
#define NHEAD 8
#define NCLASS 40
#define NEG_SLOPE 0.2f

#define N_RT 3125           // 50000/16 row tiles
#define N_RT_PAD 3128       // padded to multiple of 8 (gemm1 block = 8 rowtiles)
#define SCAN_NBLK 49        // ceil(50000/1024)

typedef __attribute__((ext_vector_type(8))) short short8;
typedef __attribute__((ext_vector_type(4))) float f32x4;

__device__ __forceinline__ float bf2f(short s) {
    return __uint_as_float(((unsigned)(unsigned short)s) << 16);
}
__device__ __forceinline__ short f2bf(float f) {
    unsigned u = __float_as_uint(f);
    unsigned r = (u + 0x7FFFu + ((u >> 16) & 1u)) >> 16;
    return (short)(unsigned short)r;
}

// ---------------- CSR build ----------------

__global__ void count_deg(const int* __restrict__ el, int* __restrict__ deg) {
    int e = blockIdx.x * blockDim.x + threadIdx.x;
    if (e < N_EDGES) atomicAdd(&deg[el[N_EDGES + e]], 1);
}

// phase 1: per-block (1024 elems) scan; local inclusive prefix -> loc, block total -> bsum
__global__ __launch_bounds__(256) void scan1(const int* __restrict__ deg,
                                             int* __restrict__ loc,
                                             int* __restrict__ bsum) {
    int tid = threadIdx.x, lane = tid & 63, w = tid >> 6;
    int base = blockIdx.x * 1024 + tid * 4;
    int d0 = (base + 0 < N_NODES) ? deg[base + 0] : 0;
    int d1 = (base + 1 < N_NODES) ? deg[base + 1] : 0;
    int d2 = (base + 2 < N_NODES) ? deg[base + 2] : 0;
    int d3 = (base + 3 < N_NODES) ? deg[base + 3] : 0;
    int s0 = d0, s1 = s0 + d1, s2 = s1 + d2, s3 = s2 + d3;
    int t = s3;
#pragma unroll
    for (int d = 1; d < 64; d <<= 1) {
        int u = __shfl_up(t, d);
        if (lane >= d) t += u;
    }
    __shared__ int wsum[4];
    if (lane == 63) wsum[w] = t;
    __syncthreads();
    int woff = 0;
#pragma unroll
    for (int j = 0; j < 4; ++j) woff += (j < w) ? wsum[j] : 0;
    int excl = woff + t - s3;                  // exclusive prefix of this thread
    if (base + 0 < N_NODES) loc[base + 0] = excl + s0;
    if (base + 1 < N_NODES) loc[base + 1] = excl + s1;
    if (base + 2 < N_NODES) loc[base + 2] = excl + s2;
    if (base + 3 < N_NODES) loc[base + 3] = excl + s3;
    if (tid == 255) bsum[blockIdx.x] = woff + t;
}

// phase 2: one wave scans the 49 block sums -> exclusive offsets
__global__ void scan2(const int* __restrict__ bsum, int* __restrict__ boff) {
    int lane = threadIdx.x;
    int v = (lane < SCAN_NBLK) ? bsum[lane] : 0;
    int t = v;
#pragma unroll
    for (int d = 1; d < 64; d <<= 1) {
        int u = __shfl_up(t, d);
        if (lane >= d) t += u;
    }
    if (lane < SCAN_NBLK) boff[lane] = t - v;
}

// phase 3: apply offsets -> ptr (shifted inclusive) and cursor (exclusive)
__global__ __launch_bounds__(256) void scan3(const int* __restrict__ deg,
                                             const int* __restrict__ loc,
                                             const int* __restrict__ boff,
                                             int* __restrict__ ptr,
                                             int* __restrict__ cursor) {
    int base = blockIdx.x * 1024 + threadIdx.x * 4;
    int off = boff[blockIdx.x];
    if (blockIdx.x == 0 && threadIdx.x == 0) ptr[0] = 0;
#pragma unroll
    for (int k = 0; k < 4; ++k) {
        int i = base + k;
        if (i < N_NODES) {
            int P = off + loc[i];
            ptr[i + 1] = P;
            cursor[i] = P - deg[i];
        }
    }
}

__global__ void scatter_k(const int* __restrict__ el, int* __restrict__ cursor,
                          int* __restrict__ esrc) {
    int e = blockIdx.x * blockDim.x + threadIdx.x;
    if (e >= N_EDGES) return;
    int dst = el[N_EDGES + e];
    int p = atomicAdd(&cursor[dst], 1);
    esrc[p] = el[e];
}

// ---------------- cast x fp32 -> bf16 in MFMA A-fragment layout ----------------
// xp[((rt*16 + ks)*64 + l)*8 + j] = x[rt*16 + (l&15)][ks*32 + (l>>4)*8 + j]
__global__ __launch_bounds__(256) void cast_x(const float* __restrict__ x,
                                              short* __restrict__ xp) {
    int t = blockIdx.x * 256 + threadIdx.x;       // < N_RT_PAD*16*64
    int l = t & 63, ks = (t >> 6) & 15, rt = t >> 10;
    short8 o;
    if (rt >= N_RT) {
#pragma unroll
        for (int j = 0; j < 8; ++j) o[j] = 0;
    } else {
        int row = rt * 16 + (l & 15);
        int col = ks * 32 + (l >> 4) * 8;
        const float* p = x + (size_t)row * NFEAT + col;
        float4 v0 = *(const float4*)p;
        float4 v1 = *(const float4*)(p + 4);
        o[0] = f2bf(v0.x); o[1] = f2bf(v0.y); o[2] = f2bf(v0.z); o[3] = f2bf(v0.w);
        o[4] = f2bf(v1.x); o[5] = f2bf(v1.y); o[6] = f2bf(v1.z); o[7] = f2bf(v1.w);
    }
    *(short8*)(xp + (size_t)t * 8) = o;
}

// ---------------- repack W1, W2 into MFMA B-fragment layout (bf16) ----------------
__global__ __launch_bounds__(256) void repack_w(const float* __restrict__ W1,
                                                const float* __restrict__ W2,
                                                short* __restrict__ Wp1,
                                                short* __restrict__ Wp2) {
    int t = blockIdx.x * 256 + threadIdx.x;
    if (t < 32768) {
        int l = t & 63, ct = (t >> 6) & 7, ks = (t >> 9) & 15, g = t >> 13;
        int c = g * 128 + ct * 16 + (l & 15);
        int head = c >> 6, f = c & 63;
        int k0 = ks * 32 + (l >> 4) * 8;
        short8 o;
#pragma unroll
        for (int j = 0; j < 8; ++j)
            o[j] = f2bf(W1[(size_t)head * NFEAT * NHID + (k0 + j) * NHID + f]);
        *(short8*)(Wp1 + (size_t)t * 8) = o;
    } else if (t < 32768 + 3072) {
        int u = t - 32768;
        int l = u & 63;
        int kc = u >> 6;                 // ks*3+ct
        int ct = kc % 3, ks = kc / 3;
        int col = ct * 16 + (l & 15);
        int k0 = ks * 32 + (l >> 4) * 8;
        short8 o;
#pragma unroll
        for (int j = 0; j < 8; ++j)
            o[j] = (col < NCLASS) ? f2bf(W2[(size_t)(k0 + j) * NCLASS + col]) : (short)0;
        *(short8*)(Wp2 + (size_t)u * 8) = o;
    }
}

// ---------------- gemm1: MFMA, no LDS. h1[n][512] bf16 row-major ----------------
__global__ __launch_bounds__(256) void gemm1(const short* __restrict__ xp,
                                             const short* __restrict__ Wp1,
                                             short* __restrict__ h1) {
    int w = threadIdx.x >> 6, l = threadIdx.x & 63;
    int g = blockIdx.x;
    int rt0 = blockIdx.y * 8 + w * 2;
    f32x4 acc[2][8];
#pragma unroll
    for (int i = 0; i < 2; ++i)
#pragma unroll
        for (int ct = 0; ct < 8; ++ct) acc[i][ct] = (f32x4){0.f, 0.f, 0.f, 0.f};

#pragma unroll 2
    for (int ks = 0; ks < 16; ++ks) {
        short8 a0 = *(const short8*)(xp + ((size_t)(rt0 * 16 + ks) * 64 + l) * 8);
        short8 a1v = *(const short8*)(xp + ((size_t)((rt0 + 1) * 16 + ks) * 64 + l) * 8);
        const short* bp = Wp1 + (size_t)(g * 16 + ks) * 4096 + l * 8;
#pragma unroll
        for (int ct = 0; ct < 8; ++ct) {
            short8 b = *(const short8*)(bp + ct * 512);
            acc[0][ct] = __builtin_amdgcn_mfma_f32_16x16x32_bf16(a0, b, acc[0][ct], 0, 0, 0);
            acc[1][ct] = __builtin_amdgcn_mfma_f32_16x16x32_bf16(a1v, b, acc[1][ct], 0, 0, 0);
        }
    }
    int colbase = g * 128 + (l & 15);
    int rbase = (l >> 4) * 4;
#pragma unroll
    for (int i = 0; i < 2; ++i)
#pragma unroll
        for (int r = 0; r < 4; ++r) {
            int row = (rt0 + i) * 16 + rbase + r;
            if (row < N_NODES) {
#pragma unroll
                for (int ct = 0; ct < 8; ++ct)
                    h1[(size_t)row * 512 + colbase + ct * 16] = f2bf(acc[i][ct][r]);
            }
        }
}

// ---------------- s1 scores: wave per node, all heads; lane = 8 contig feats ----------------
__global__ __launch_bounds__(256) void s1_kernel(const short* __restrict__ h1,
                                                 const float* __restrict__ a1,
                                                 float* __restrict__ s1s,
                                                 float* __restrict__ s1d) {
    int n = blockIdx.x * 4 + (threadIdx.x >> 6);
    int l = threadIdx.x & 63;
    if (n >= N_NODES) return;
    short8 hv = *(const short8*)(h1 + (size_t)n * 512 + l * 8);
    int h = l >> 3, fb = (l & 7) * 8;
    float ps = 0.f, pd = 0.f;
#pragma unroll
    for (int j = 0; j < 8; ++j) {
        float v = bf2f(hv[j]);
        ps += v * a1[h * 128 + fb + j];
        pd += v * a1[h * 128 + 64 + fb + j];
    }
#pragma unroll
    for (int mask = 1; mask < 8; mask <<= 1) {
        ps += __shfl_xor(ps, mask);
        pd += __shfl_xor(pd, mask);
    }
    if ((l & 7) == 0) { s1s[n * 8 + h] = ps; s1d[n * 8 + h] = pd; }
}

// ---------------- fused layer-1 attention: wave per dst, ALL heads ----------------
__global__ __launch_bounds__(256) void att1(const int* __restrict__ ptr,
                                            const int* __restrict__ esrc,
                                            const float* __restrict__ s1s,
                                            const float* __restrict__ s1d,
                                            const short* __restrict__ h1,
                                            const float* __restrict__ b1,
                                            short* __restrict__ hcatp) {
    int n = blockIdx.x * 4 + (threadIdx.x >> 6);
    int l = threadIdx.x & 63;
    if (n >= N_NODES) return;
    int beg = ptr[n], end = ptr[n + 1];
    int h = l >> 3;
    float sd = s1d[n * 8 + h];
    float m = -INFINITY, den = 0.f;
    float acc[8] = {0.f, 0.f, 0.f, 0.f, 0.f, 0.f, 0.f, 0.f};
    for (int i = beg; i < end; ++i) {
        int src = esrc[i];
        float sc = s1s[src * 8 + h] + sd;
        sc = sc > 0.f ? sc : NEG_SLOPE * sc;
        float nm = fmaxf(m, sc);
        float scale = __expf(m - nm);     // first iter: exp(-inf)=0
        float wgt = __expf(sc - nm);
        den = den * scale + wgt;
        short8 hv = *(const short8*)(h1 + (size_t)src * 512 + l * 8);
#pragma unroll
        for (int j = 0; j < 8; ++j) acc[j] = acc[j] * scale + wgt * bf2f(hv[j]);
        m = nm;
    }
    float rden = 1.f / fmaxf(den, 1e-16f);
    short8 o;
#pragma unroll
    for (int j = 0; j < 8; ++j) {
        float v = acc[j] * rden + b1[l * 8 + j];
        v = v > 0.f ? v : (__expf(v) - 1.f);      // ELU
        o[j] = f2bf(v);
    }
    // frag layout: rt=n>>4, ks=l>>2, lane'=(l&3)*16+(n&15), j contiguous
    size_t addr = (((size_t)(n >> 4) * 16 + (l >> 2)) * 64 + (l & 3) * 16 + (n & 15)) * 8;
    *(short8*)(hcatp + addr) = o;
}

// ---------------- gemm2: MFMA + fused s2 scores. wave per rowtile ----------------
__global__ __launch_bounds__(256) void gemm2(const short* __restrict__ hcatp,
                                             const short* __restrict__ Wp2,
                                             const float* __restrict__ a2,
                                             short* __restrict__ h2,
                                             float* __restrict__ s2s,
                                             float* __restrict__ s2d) {
    int w = threadIdx.x >> 6, l = threadIdx.x & 63;
    int rt = blockIdx.x * 4 + w;                  // < N_RT_PAD
    f32x4 acc[3];
#pragma unroll
    for (int ct = 0; ct < 3; ++ct) acc[ct] = (f32x4){0.f, 0.f, 0.f, 0.f};
#pragma unroll 2
    for (int ks = 0; ks < 16; ++ks) {
        short8 a = *(const short8*)(hcatp + ((size_t)(rt * 16 + ks) * 64 + l) * 8);
        const short* bp = Wp2 + (size_t)(ks * 3) * 512 + l * 8;
#pragma unroll
        for (int ct = 0; ct < 3; ++ct) {
            short8 b = *(const short8*)(bp + ct * 512);
            acc[ct] = __builtin_amdgcn_mfma_f32_16x16x32_bf16(a, b, acc[ct], 0, 0, 0);
        }
    }
    float ps[4] = {0.f, 0.f, 0.f, 0.f}, pd[4] = {0.f, 0.f, 0.f, 0.f};
    int cl = l & 15, rb = (l >> 4) * 4;
#pragma unroll
    for (int ct = 0; ct < 3; ++ct) {
        int col = ct * 16 + cl;
        if (col < NCLASS) {
#pragma unroll
            for (int r = 0; r < 4; ++r) {
                ps[r] += acc[ct][r] * a2[col];
                pd[r] += acc[ct][r] * a2[NCLASS + col];
                int row = rt * 16 + rb + r;
                if (row < N_NODES) h2[(size_t)row * NCLASS + col] = f2bf(acc[ct][r]);
            }
        }
    }
#pragma unroll
    for (int mask = 1; mask < 16; mask <<= 1)
#pragma unroll
        for (int r = 0; r < 4; ++r) {
            ps[r] += __shfl_xor(ps[r], mask);
            pd[r] += __shfl_xor(pd[r], mask);
        }
    if (cl == 0) {
#pragma unroll
        for (int r = 0; r < 4; ++r) {
            int row = rt * 16 + rb + r;
            if (row < N_NODES) { s2s[row] = ps[r]; s2d[row] = pd[r]; }
        }
    }
}

// ---------------- fused layer-2 attention + log_softmax: wave per dst ----------------
__global__ __launch_bounds__(256) void att2(const int* __restrict__ ptr,
                                            const int* __restrict__ esrc,
                                            const float* __restrict__ s2s,
                                            const float* __restrict__ s2d,
                                            const short* __restrict__ h2,
                                            const float* __restrict__ b2,
                                            float* __restrict__ out) {
    int n = blockIdx.x * 4 + (threadIdx.x >> 6);
    int l = threadIdx.x & 63;
    if (n >= N_NODES) return;
    int beg = ptr[n], end = ptr[n + 1];
    float sd = s2d[n];
    float m = -INFINITY, den = 0.f, acc = 0.f;
    for (int i = beg; i < end; ++i) {
        int src = esrc[i];
        float sc = s2s[src] + sd;
        sc = sc > 0.f ? sc : NEG_SLOPE * sc;
        float nm = fmaxf(m, sc);
        float scale = __expf(m - nm);
        float wgt = __expf(sc - nm);
        float hv = (l < NCLASS) ? bf2f(h2[(size_t)src * NCLASS + l]) : 0.f;
        den = den * scale + wgt;
        acc = acc * scale + wgt * hv;
        m = nm;
    }
    float v = (l < NCLASS) ? acc / fmaxf(den, 1e-16f) + b2[l] : -INFINITY;
    float mx = v;
#pragma unroll
    for (int o = 32; o; o >>= 1) mx = fmaxf(mx, __shfl_down(mx, o));
    mx = __shfl(mx, 0);
    float ex = (l < NCLASS) ? __expf(v - mx) : 0.f;
    float s = ex;
#pragma unroll
    for (int o = 32; o; o >>= 1) s += __shfl_down(s, o);
    s = __shfl(s, 0);
    float ls = __logf(s);
    if (l < NCLASS) out[(size_t)n * NCLASS + l] = v - mx - ls;
}

// ---------------- launch ----------------

extern "C" void kernel_launch(void* const* d_in, const int* in_sizes, int n_in,
                              void* d_out, int out_size, void* d_ws, size_t ws_size,
                              hipStream_t stream) {
    const float* x  = (const float*)d_in[0];
    const int*   el = (const int*)d_in[1];
    const float* W1 = (const float*)d_in[2];
    const float* a1 = (const float*)d_in[3];
    const float* b1 = (const float*)d_in[4];
    const float* W2 = (const float*)d_in[5];
    const float* a2 = (const float*)d_in[6];
    const float* b2 = (const float*)d_in[7];
    float* out = (float*)d_out;

    // workspace carve (shorts first, then floats, then ints)
    short* sbase = (short*)d_ws;
    short* xp    = sbase;                          // 25,624,576
    short* hcatp = sbase + 25624576;               // 25,624,576
    short* h1    = sbase + 51249152;               // 25,600,000
    short* Wp1   = sbase + 76849152;               //    262,144
    short* Wp2   = sbase + 77111296;               //     24,576
    short* h2    = sbase + 77135872;               //  2,000,000
    float* fbase = (float*)(sbase + 79135872);
    float* s1s   = fbase;                          //    400,000
    float* s1d   = fbase + 400000;                 //    400,000
    float* s2s   = fbase + 800000;                 //     50,000
    float* s2d   = fbase + 850000;                 //     50,000
    int*   ibase = (int*)(fbase + 900000);
    int*   deg    = ibase;                         //     50,000
    int*   ptr    = ibase + 50000;                 //     50,001
    int*   cursor = ibase + 100001;                //     50,000
    int*   esrc   = ibase + 150001;                //    800,000
    int*   loc    = ibase + 950001;                //     50,000
    int*   bsum   = ibase + 1000001;               //         64
    int*   boff   = ibase + 1000065;               //         64
    // total ~170 MB

    // ---- CSR build ----
    hipMemsetAsync(deg, 0, (size_t)N_NODES * 4, stream);
    count_deg<<<(N_EDGES + 255) / 256, 256, 0, stream>>>(el, deg);
    scan1<<<SCAN_NBLK, 256, 0, stream>>>(deg, loc, bsum);
    scan2<<<1, 64, 0, stream>>>(bsum, boff);
    scan3<<<SCAN_NBLK, 256, 0, stream>>>(deg, loc, boff, ptr, cursor);
    scatter_k<<<(N_EDGES + 255) / 256, 256, 0, stream>>>(el, cursor, esrc);

    // ---- operand packing ----
    cast_x<<<(N_RT_PAD * 1024) / 256, 256, 0, stream>>>(x, xp);
    repack_w<<<(35840 + 255) / 256, 256, 0, stream>>>(W1, W2, Wp1, Wp2);

    // ---- layer 1 ----
    gemm1<<<dim3(4, N_RT_PAD / 8), 256, 0, stream>>>(xp, Wp1, h1);
    s1_kernel<<<(N_NODES + 3) / 4, 256, 0, stream>>>(h1, a1, s1s, s1d);
    att1<<<(N_NODES + 3) / 4, 256, 0, stream>>>(ptr, esrc, s1s, s1d, h1, b1, hcatp);

    // ---- layer 2 ----
    gemm2<<<N_RT_PAD / 4, 256, 0, stream>>>(hcatp, Wp2, a2, h2, s2s, s2d);
    att2<<<(N_NODES + 3) / 4, 256, 0, stream>>>(ptr, esrc, s2s, s2d, h2, b2, out);
}

// Round 5
// 562.136 us; speedup vs baseline: 5.1454x; 1.1018x over previous
//
#include <hip/hip_runtime.h>
#include <math.h>

#define N_NODES 50000
#define N_EDGES 800000
#define NFEAT 512
#define NHID 64
#define NHEAD 8
#define NCLASS 40
#define NEG_SLOPE 0.2f

#define N_RT 3125           // 50000/16 row tiles
#define N_RT_PAD 3128       // padded to multiple of 8 (gemm1 block = 8 rowtiles)
#define SCAN_NBLK 49        // ceil(50000/1024)

typedef __attribute__((ext_vector_type(8))) short short8;
typedef __attribute__((ext_vector_type(4))) float f32x4;

__device__ __forceinline__ float bf2f(short s) {
    return __uint_as_float(((unsigned)(unsigned short)s) << 16);
}
__device__ __forceinline__ short f2bf(float f) {
    unsigned u = __float_as_uint(f);
    unsigned r = (u + 0x7FFFu + ((u >> 16) & 1u)) >> 16;
    return (short)(unsigned short)r;
}

// ---------------- CSR build ----------------

__global__ void count_deg(const int* __restrict__ el, int* __restrict__ deg) {
    int e = blockIdx.x * blockDim.x + threadIdx.x;
    if (e < N_EDGES) atomicAdd(&deg[el[N_EDGES + e]], 1);
}

// phase 1: per-block (1024 elems) scan; local inclusive prefix -> loc, block total -> bsum
__global__ __launch_bounds__(256) void scan1(const int* __restrict__ deg,
                                             int* __restrict__ loc,
                                             int* __restrict__ bsum) {
    int tid = threadIdx.x, lane = tid & 63, w = tid >> 6;
    int base = blockIdx.x * 1024 + tid * 4;
    int d0 = (base + 0 < N_NODES) ? deg[base + 0] : 0;
    int d1 = (base + 1 < N_NODES) ? deg[base + 1] : 0;
    int d2 = (base + 2 < N_NODES) ? deg[base + 2] : 0;
    int d3 = (base + 3 < N_NODES) ? deg[base + 3] : 0;
    int s0 = d0, s1 = s0 + d1, s2 = s1 + d2, s3 = s2 + d3;
    int t = s3;
#pragma unroll
    for (int d = 1; d < 64; d <<= 1) {
        int u = __shfl_up(t, d);
        if (lane >= d) t += u;
    }
    __shared__ int wsum[4];
    if (lane == 63) wsum[w] = t;
    __syncthreads();
    int woff = 0;
#pragma unroll
    for (int j = 0; j < 4; ++j) woff += (j < w) ? wsum[j] : 0;
    int excl = woff + t - s3;                  // exclusive prefix of this thread
    if (base + 0 < N_NODES) loc[base + 0] = excl + s0;
    if (base + 1 < N_NODES) loc[base + 1] = excl + s1;
    if (base + 2 < N_NODES) loc[base + 2] = excl + s2;
    if (base + 3 < N_NODES) loc[base + 3] = excl + s3;
    if (tid == 255) bsum[blockIdx.x] = woff + t;
}

// phase 2: one wave scans the 49 block sums -> exclusive offsets
__global__ void scan2(const int* __restrict__ bsum, int* __restrict__ boff) {
    int lane = threadIdx.x;
    int v = (lane < SCAN_NBLK) ? bsum[lane] : 0;
    int t = v;
#pragma unroll
    for (int d = 1; d < 64; d <<= 1) {
        int u = __shfl_up(t, d);
        if (lane >= d) t += u;
    }
    if (lane < SCAN_NBLK) boff[lane] = t - v;
}

// phase 3: apply offsets -> ptr (shifted inclusive) and cursor (exclusive)
__global__ __launch_bounds__(256) void scan3(const int* __restrict__ deg,
                                             const int* __restrict__ loc,
                                             const int* __restrict__ boff,
                                             int* __restrict__ ptr,
                                             int* __restrict__ cursor) {
    int base = blockIdx.x * 1024 + threadIdx.x * 4;
    int off = boff[blockIdx.x];
    if (blockIdx.x == 0 && threadIdx.x == 0) ptr[0] = 0;
#pragma unroll
    for (int k = 0; k < 4; ++k) {
        int i = base + k;
        if (i < N_NODES) {
            int P = off + loc[i];
            ptr[i + 1] = P;
            cursor[i] = P - deg[i];
        }
    }
}

__global__ void scatter_k(const int* __restrict__ el, int* __restrict__ cursor,
                          int* __restrict__ esrc) {
    int e = blockIdx.x * blockDim.x + threadIdx.x;
    if (e >= N_EDGES) return;
    int dst = el[N_EDGES + e];
    int p = atomicAdd(&cursor[dst], 1);
    esrc[p] = el[e];
}

// ---------------- cast x fp32 -> bf16 in MFMA A-fragment layout ----------------
// xp[((rt*16 + ks)*64 + l)*8 + j] = x[rt*16 + (l&15)][ks*32 + (l>>4)*8 + j]
__global__ __launch_bounds__(256) void cast_x(const float* __restrict__ x,
                                              short* __restrict__ xp) {
    int t = blockIdx.x * 256 + threadIdx.x;       // < N_RT_PAD*16*64
    int l = t & 63, ks = (t >> 6) & 15, rt = t >> 10;
    short8 o;
    if (rt >= N_RT) {
#pragma unroll
        for (int j = 0; j < 8; ++j) o[j] = 0;
    } else {
        int row = rt * 16 + (l & 15);
        int col = ks * 32 + (l >> 4) * 8;
        const float* p = x + (size_t)row * NFEAT + col;
        float4 v0 = *(const float4*)p;
        float4 v1 = *(const float4*)(p + 4);
        o[0] = f2bf(v0.x); o[1] = f2bf(v0.y); o[2] = f2bf(v0.z); o[3] = f2bf(v0.w);
        o[4] = f2bf(v1.x); o[5] = f2bf(v1.y); o[6] = f2bf(v1.z); o[7] = f2bf(v1.w);
    }
    *(short8*)(xp + (size_t)t * 8) = o;
}

// ---------------- repack W1, W2 into MFMA B-fragment layout (bf16) ----------------
__global__ __launch_bounds__(256) void repack_w(const float* __restrict__ W1,
                                                const float* __restrict__ W2,
                                                short* __restrict__ Wp1,
                                                short* __restrict__ Wp2) {
    int t = blockIdx.x * 256 + threadIdx.x;
    if (t < 32768) {
        int l = t & 63, ct = (t >> 6) & 7, ks = (t >> 9) & 15, g = t >> 13;
        int c = g * 128 + ct * 16 + (l & 15);
        int head = c >> 6, f = c & 63;
        int k0 = ks * 32 + (l >> 4) * 8;
        short8 o;
#pragma unroll
        for (int j = 0; j < 8; ++j)
            o[j] = f2bf(W1[(size_t)head * NFEAT * NHID + (k0 + j) * NHID + f]);
        *(short8*)(Wp1 + (size_t)t * 8) = o;
    } else if (t < 32768 + 3072) {
        int u = t - 32768;
        int l = u & 63;
        int kc = u >> 6;                 // ks*3+ct
        int ct = kc % 3, ks = kc / 3;
        int col = ct * 16 + (l & 15);
        int k0 = ks * 32 + (l >> 4) * 8;
        short8 o;
#pragma unroll
        for (int j = 0; j < 8; ++j)
            o[j] = (col < NCLASS) ? f2bf(W2[(size_t)(k0 + j) * NCLASS + col]) : (short)0;
        *(short8*)(Wp2 + (size_t)u * 8) = o;
    }
}

// ---------------- gemm1: MFMA, no LDS + fused s1 scores ----------------
// h1[n][512] bf16 row-major; s1s/s1d computed from fp32 acc in epilogue.
__global__ __launch_bounds__(256) void gemm1(const short* __restrict__ xp,
                                             const short* __restrict__ Wp1,
                                             const float* __restrict__ a1,
                                             short* __restrict__ h1,
                                             float* __restrict__ s1s,
                                             float* __restrict__ s1d) {
    int w = threadIdx.x >> 6, l = threadIdx.x & 63;
    int g = blockIdx.x;
    int rt0 = blockIdx.y * 8 + w * 2;
    f32x4 acc[2][8];
#pragma unroll
    for (int i = 0; i < 2; ++i)
#pragma unroll
        for (int ct = 0; ct < 8; ++ct) acc[i][ct] = (f32x4){0.f, 0.f, 0.f, 0.f};

#pragma unroll 2
    for (int ks = 0; ks < 16; ++ks) {
        short8 a0 = *(const short8*)(xp + ((size_t)(rt0 * 16 + ks) * 64 + l) * 8);
        short8 a1v = *(const short8*)(xp + ((size_t)((rt0 + 1) * 16 + ks) * 64 + l) * 8);
        const short* bp = Wp1 + (size_t)(g * 16 + ks) * 4096 + l * 8;
#pragma unroll
        for (int ct = 0; ct < 8; ++ct) {
            short8 b = *(const short8*)(bp + ct * 512);
            acc[0][ct] = __builtin_amdgcn_mfma_f32_16x16x32_bf16(a0, b, acc[0][ct], 0, 0, 0);
            acc[1][ct] = __builtin_amdgcn_mfma_f32_16x16x32_bf16(a1v, b, acc[1][ct], 0, 0, 0);
        }
    }
    // per-lane attention-vector values (head = 2g + (ct>=4), f = (ct&3)*16 + (l&15))
    float avs[8], avd[8];
#pragma unroll
    for (int ct = 0; ct < 8; ++ct) {
        int head = 2 * g + (ct >> 2);
        int f = (ct & 3) * 16 + (l & 15);
        avs[ct] = a1[head * 128 + f];
        avd[ct] = a1[head * 128 + 64 + f];
    }
    int colbase = g * 128 + (l & 15);
    int rbase = (l >> 4) * 4;
#pragma unroll
    for (int i = 0; i < 2; ++i)
#pragma unroll
        for (int r = 0; r < 4; ++r) {
            int row = (rt0 + i) * 16 + rbase + r;
            float ps0 = 0.f, pd0 = 0.f, ps1 = 0.f, pd1 = 0.f;
#pragma unroll
            for (int ct = 0; ct < 4; ++ct) {
                ps0 += acc[i][ct][r] * avs[ct];
                pd0 += acc[i][ct][r] * avd[ct];
            }
#pragma unroll
            for (int ct = 4; ct < 8; ++ct) {
                ps1 += acc[i][ct][r] * avs[ct];
                pd1 += acc[i][ct][r] * avd[ct];
            }
#pragma unroll
            for (int mask = 1; mask < 16; mask <<= 1) {
                ps0 += __shfl_xor(ps0, mask);
                pd0 += __shfl_xor(pd0, mask);
                ps1 += __shfl_xor(ps1, mask);
                pd1 += __shfl_xor(pd1, mask);
            }
            if (row < N_NODES) {
                if ((l & 15) == 0) {
                    s1s[row * 8 + 2 * g]     = ps0;
                    s1d[row * 8 + 2 * g]     = pd0;
                    s1s[row * 8 + 2 * g + 1] = ps1;
                    s1d[row * 8 + 2 * g + 1] = pd1;
                }
#pragma unroll
                for (int ct = 0; ct < 8; ++ct)
                    h1[(size_t)row * 512 + colbase + ct * 16] = f2bf(acc[i][ct][r]);
            }
        }
}

// ---------------- fused layer-1 attention: wave per dst, ALL heads ----------------
// direct exp (softmax shift-invariance; scores are O(10) -> no overflow), 1-deep prefetch
__global__ __launch_bounds__(256) void att1(const int* __restrict__ ptr,
                                            const int* __restrict__ esrc,
                                            const float* __restrict__ s1s,
                                            const float* __restrict__ s1d,
                                            const short* __restrict__ h1,
                                            const float* __restrict__ b1,
                                            short* __restrict__ hcatp) {
    int n = blockIdx.x * 4 + (threadIdx.x >> 6);
    int l = threadIdx.x & 63;
    if (n >= N_NODES) return;
    int beg = ptr[n], end = ptr[n + 1];
    int h = l >> 3;
    float sd = s1d[n * 8 + h];
    float den = 0.f;
    float acc[8] = {0.f, 0.f, 0.f, 0.f, 0.f, 0.f, 0.f, 0.f};
    if (beg < end) {
        int src = esrc[beg];
        short8 hv = *(const short8*)(h1 + (size_t)src * 512 + l * 8);
        float ss = s1s[src * 8 + h];
        for (int i = beg; i < end; ++i) {
            int ip = (i + 1 < end) ? i + 1 : i;
            int nsrc = esrc[ip];
            short8 nhv = *(const short8*)(h1 + (size_t)nsrc * 512 + l * 8);
            float nss = s1s[nsrc * 8 + h];
            float sc = ss + sd;
            sc = fmaxf(sc, NEG_SLOPE * sc);     // leaky relu (slope<1)
            float wgt = __expf(sc);
            den += wgt;
#pragma unroll
            for (int j = 0; j < 8; ++j) acc[j] += wgt * bf2f(hv[j]);
            hv = nhv; ss = nss;
        }
    }
    float rden = 1.f / fmaxf(den, 1e-16f);
    short8 o;
#pragma unroll
    for (int j = 0; j < 8; ++j) {
        float v = acc[j] * rden + b1[l * 8 + j];
        v = v > 0.f ? v : (__expf(v) - 1.f);    // ELU
        o[j] = f2bf(v);
    }
    // frag layout: rt=n>>4, ks=l>>2, lane'=(l&3)*16+(n&15), j contiguous
    size_t addr = (((size_t)(n >> 4) * 16 + (l >> 2)) * 64 + (l & 3) * 16 + (n & 15)) * 8;
    *(short8*)(hcatp + addr) = o;
}

// ---------------- gemm2: MFMA + fused s2 scores. wave per rowtile ----------------
__global__ __launch_bounds__(256) void gemm2(const short* __restrict__ hcatp,
                                             const short* __restrict__ Wp2,
                                             const float* __restrict__ a2,
                                             short* __restrict__ h2,
                                             float* __restrict__ s2s,
                                             float* __restrict__ s2d) {
    int w = threadIdx.x >> 6, l = threadIdx.x & 63;
    int rt = blockIdx.x * 4 + w;                  // < N_RT_PAD
    f32x4 acc[3];
#pragma unroll
    for (int ct = 0; ct < 3; ++ct) acc[ct] = (f32x4){0.f, 0.f, 0.f, 0.f};
#pragma unroll 2
    for (int ks = 0; ks < 16; ++ks) {
        short8 a = *(const short8*)(hcatp + ((size_t)(rt * 16 + ks) * 64 + l) * 8);
        const short* bp = Wp2 + (size_t)(ks * 3) * 512 + l * 8;
#pragma unroll
        for (int ct = 0; ct < 3; ++ct) {
            short8 b = *(const short8*)(bp + ct * 512);
            acc[ct] = __builtin_amdgcn_mfma_f32_16x16x32_bf16(a, b, acc[ct], 0, 0, 0);
        }
    }
    float ps[4] = {0.f, 0.f, 0.f, 0.f}, pd[4] = {0.f, 0.f, 0.f, 0.f};
    int cl = l & 15, rb = (l >> 4) * 4;
#pragma unroll
    for (int ct = 0; ct < 3; ++ct) {
        int col = ct * 16 + cl;
        if (col < NCLASS) {
#pragma unroll
            for (int r = 0; r < 4; ++r) {
                ps[r] += acc[ct][r] * a2[col];
                pd[r] += acc[ct][r] * a2[NCLASS + col];
                int row = rt * 16 + rb + r;
                if (row < N_NODES) h2[(size_t)row * NCLASS + col] = f2bf(acc[ct][r]);
            }
        }
    }
#pragma unroll
    for (int mask = 1; mask < 16; mask <<= 1)
#pragma unroll
        for (int r = 0; r < 4; ++r) {
            ps[r] += __shfl_xor(ps[r], mask);
            pd[r] += __shfl_xor(pd[r], mask);
        }
    if (cl == 0) {
#pragma unroll
        for (int r = 0; r < 4; ++r) {
            int row = rt * 16 + rb + r;
            if (row < N_NODES) { s2s[row] = ps[r]; s2d[row] = pd[r]; }
        }
    }
}

// ---------------- fused layer-2 attention + log_softmax: wave per dst ----------------
__global__ __launch_bounds__(256) void att2(const int* __restrict__ ptr,
                                            const int* __restrict__ esrc,
                                            const float* __restrict__ s2s,
                                            const float* __restrict__ s2d,
                                            const short* __restrict__ h2,
                                            const float* __restrict__ b2,
                                            float* __restrict__ out) {
    int n = blockIdx.x * 4 + (threadIdx.x >> 6);
    int l = threadIdx.x & 63;
    if (n >= N_NODES) return;
    int beg = ptr[n], end = ptr[n + 1];
    float sd = s2d[n];
    float den = 0.f, acc = 0.f;
    if (beg < end) {
        int src = esrc[beg];
        float hv = (l < NCLASS) ? bf2f(h2[(size_t)src * NCLASS + l]) : 0.f;
        float ss = s2s[src];
        for (int i = beg; i < end; ++i) {
            int ip = (i + 1 < end) ? i + 1 : i;
            int nsrc = esrc[ip];
            float nhv = (l < NCLASS) ? bf2f(h2[(size_t)nsrc * NCLASS + l]) : 0.f;
            float nss = s2s[nsrc];
            float sc = ss + sd;
            sc = fmaxf(sc, NEG_SLOPE * sc);
            float wgt = __expf(sc);
            den += wgt;
            acc += wgt * hv;
            hv = nhv; ss = nss;
        }
    }
    float v = (l < NCLASS) ? acc / fmaxf(den, 1e-16f) + b2[l] : -INFINITY;
    float mx = v;
#pragma unroll
    for (int o = 32; o; o >>= 1) mx = fmaxf(mx, __shfl_down(mx, o));
    mx = __shfl(mx, 0);
    float ex = (l < NCLASS) ? __expf(v - mx) : 0.f;
    float s = ex;
#pragma unroll
    for (int o = 32; o; o >>= 1) s += __shfl_down(s, o);
    s = __shfl(s, 0);
    float ls = __logf(s);
    if (l < NCLASS) out[(size_t)n * NCLASS + l] = v - mx - ls;
}

// ---------------- launch ----------------

extern "C" void kernel_launch(void* const* d_in, const int* in_sizes, int n_in,
                              void* d_out, int out_size, void* d_ws, size_t ws_size,
                              hipStream_t stream) {
    const float* x  = (const float*)d_in[0];
    const int*   el = (const int*)d_in[1];
    const float* W1 = (const float*)d_in[2];
    const float* a1 = (const float*)d_in[3];
    const float* b1 = (const float*)d_in[4];
    const float* W2 = (const float*)d_in[5];
    const float* a2 = (const float*)d_in[6];
    const float* b2 = (const float*)d_in[7];
    float* out = (float*)d_out;

    // workspace carve (shorts first, then floats, then ints)
    short* sbase = (short*)d_ws;
    short* xp    = sbase;                          // 25,624,576
    short* hcatp = sbase + 25624576;               // 25,624,576
    short* h1    = sbase + 51249152;               // 25,600,000
    short* Wp1   = sbase + 76849152;               //    262,144
    short* Wp2   = sbase + 77111296;               //     24,576
    short* h2    = sbase + 77135872;               //  2,000,000
    float* fbase = (float*)(sbase + 79135872);
    float* s1s   = fbase;                          //    400,000
    float* s1d   = fbase + 400000;                 //    400,000
    float* s2s   = fbase + 800000;                 //     50,000
    float* s2d   = fbase + 850000;                 //     50,000
    int*   ibase = (int*)(fbase + 900000);
    int*   deg    = ibase;                         //     50,000
    int*   ptr    = ibase + 50000;                 //     50,001
    int*   cursor = ibase + 100001;                //     50,000
    int*   esrc   = ibase + 150001;                //    800,000
    int*   loc    = ibase + 950001;                //     50,000
    int*   bsum   = ibase + 1000001;               //         64
    int*   boff   = ibase + 1000065;               //         64
    // total ~170 MB

    // ---- CSR build ----
    hipMemsetAsync(deg, 0, (size_t)N_NODES * 4, stream);
    count_deg<<<(N_EDGES + 255) / 256, 256, 0, stream>>>(el, deg);
    scan1<<<SCAN_NBLK, 256, 0, stream>>>(deg, loc, bsum);
    scan2<<<1, 64, 0, stream>>>(bsum, boff);
    scan3<<<SCAN_NBLK, 256, 0, stream>>>(deg, loc, boff, ptr, cursor);
    scatter_k<<<(N_EDGES + 255) / 256, 256, 0, stream>>>(el, cursor, esrc);

    // ---- operand packing ----
    cast_x<<<(N_RT_PAD * 1024) / 256, 256, 0, stream>>>(x, xp);
    repack_w<<<(35840 + 255) / 256, 256, 0, stream>>>(W1, W2, Wp1, Wp2);

    // ---- layer 1 ----
    gemm1<<<dim3(4, N_RT_PAD / 8), 256, 0, stream>>>(xp, Wp1, a1, h1, s1s, s1d);
    att1<<<(N_NODES + 3) / 4, 256, 0, stream>>>(ptr, esrc, s1s, s1d, h1, b1, hcatp);

    // ---- layer 2 ----
    gemm2<<<N_RT_PAD / 4, 256, 0, stream>>>(hcatp, Wp2, a2, h2, s2s, s2d);
    att2<<<(N_NODES + 3) / 4, 256, 0, stream>>>(ptr, esrc, s2s, s2d, h2, b2, out);
}